// Round 1
// baseline (989.745 us; speedup 1.0000x reference)
//
#include <hip/hip_runtime.h>

#define N_NODES 100000
#define N_EDGES 1000000
#define EPS 1e-5f
#define SLOPE 0.01f

// ---------------------------------------------------------------------------
// Kernel 1: per-edge message computation + atomic scatter
// msg[e, o] = sum_i v[src][i] * ( b[i*16+o] + sum_k e[e,k] * W[(i*16+o)*4 + k] )
// W/b indices are wave-uniform -> expect s_load + SGPR-operand v_fma.
// ---------------------------------------------------------------------------
__global__ __launch_bounds__(256) void edge_kernel(
    const float* __restrict__ v,
    const float* __restrict__ efeat,
    const int* __restrict__ edge_index,
    const float* __restrict__ enet_w,
    const float* __restrict__ enet_b,
    float* __restrict__ summed,
    float* __restrict__ cnt)
{
    int eid = blockIdx.x * 256 + threadIdx.x;
    if (eid >= N_EDGES) return;

    int src = edge_index[eid];
    int dst = edge_index[N_EDGES + eid];

    float4 ef = *(const float4*)(efeat + (size_t)eid * 4);

    float vsrc[16];
    #pragma unroll
    for (int i = 0; i < 4; ++i) {
        float4 t = *(const float4*)(v + (size_t)src * 16 + i * 4);
        vsrc[i * 4 + 0] = t.x;
        vsrc[i * 4 + 1] = t.y;
        vsrc[i * 4 + 2] = t.z;
        vsrc[i * 4 + 3] = t.w;
    }

    float acc[16];
    #pragma unroll
    for (int o = 0; o < 16; ++o) acc[o] = 0.0f;

    #pragma unroll
    for (int i = 0; i < 16; ++i) {
        float vi = vsrc[i];
        #pragma unroll
        for (int o = 0; o < 16; ++o) {
            const int r = i * 16 + o;
            float w = enet_b[r];
            w = fmaf(ef.x, enet_w[r * 4 + 0], w);
            w = fmaf(ef.y, enet_w[r * 4 + 1], w);
            w = fmaf(ef.z, enet_w[r * 4 + 2], w);
            w = fmaf(ef.w, enet_w[r * 4 + 3], w);
            acc[o] = fmaf(vi, w, acc[o]);
        }
    }

    float* sbase = summed + (size_t)dst * 16;
    #pragma unroll
    for (int o = 0; o < 16; ++o) atomicAdd(sbase + o, acc[o]);
    atomicAdd(cnt + dst, 1.0f);
}

// ---------------------------------------------------------------------------
// Kernel 2: per-node: mean + root transform + bias -> d_out (pre-BN),
// plus per-column sum / sumsq reduction into stats[32].
// ---------------------------------------------------------------------------
__global__ __launch_bounds__(256) void node_kernel(
    const float* __restrict__ v,
    const float* __restrict__ summed,
    const float* __restrict__ cnt,
    const float* __restrict__ root,
    const float* __restrict__ bias,
    float* __restrict__ out,
    float* __restrict__ stats)
{
    int n = blockIdx.x * 256 + threadIdx.x;
    bool active = (n < N_NODES);

    float val[16];
    if (active) {
        float vn[16];
        #pragma unroll
        for (int i = 0; i < 4; ++i) {
            float4 t = *(const float4*)(v + (size_t)n * 16 + i * 4);
            vn[i * 4 + 0] = t.x;
            vn[i * 4 + 1] = t.y;
            vn[i * 4 + 2] = t.z;
            vn[i * 4 + 3] = t.w;
        }
        float c = cnt[n];
        float scale = 1.0f / fmaxf(c, 1.0f);
        #pragma unroll
        for (int o = 0; o < 16; ++o) {
            float a = fmaf(summed[(size_t)n * 16 + o], scale, bias[o]);
            #pragma unroll
            for (int i = 0; i < 16; ++i)
                a = fmaf(vn[i], root[i * 16 + o], a);
            val[o] = a;
        }
        #pragma unroll
        for (int i = 0; i < 4; ++i) {
            float4 t = make_float4(val[i * 4 + 0], val[i * 4 + 1],
                                   val[i * 4 + 2], val[i * 4 + 3]);
            *(float4*)(out + (size_t)n * 16 + i * 4) = t;
        }
    } else {
        #pragma unroll
        for (int o = 0; o < 16; ++o) val[o] = 0.0f;
    }

    // wave-level butterfly reduction of sum and sumsq per column
    float ssum[16], ssq[16];
    #pragma unroll
    for (int o = 0; o < 16; ++o) {
        float a = val[o];
        float b = a * a;
        #pragma unroll
        for (int m = 1; m < 64; m <<= 1) {
            a += __shfl_xor(a, m, 64);
            b += __shfl_xor(b, m, 64);
        }
        ssum[o] = a;
        ssq[o] = b;
    }

    __shared__ float part[4][32];
    int wave = threadIdx.x >> 6;
    int lane = threadIdx.x & 63;
    if (lane == 0) {
        #pragma unroll
        for (int o = 0; o < 16; ++o) {
            part[wave][o] = ssum[o];
            part[wave][16 + o] = ssq[o];
        }
    }
    __syncthreads();
    if (threadIdx.x < 32) {
        float t = part[0][threadIdx.x] + part[1][threadIdx.x] +
                  part[2][threadIdx.x] + part[3][threadIdx.x];
        atomicAdd(stats + threadIdx.x, t);
    }
}

// ---------------------------------------------------------------------------
// Kernel 3: BatchNorm (batch stats) + LeakyReLU, in place on d_out.
// ---------------------------------------------------------------------------
__global__ __launch_bounds__(256) void final_kernel(
    float* __restrict__ out,
    const float* __restrict__ stats,
    const float* __restrict__ gamma,
    const float* __restrict__ beta)
{
    int idx = blockIdx.x * 256 + threadIdx.x;
    if (idx >= N_NODES * 16) return;
    int o = idx & 15;
    const float invN = 1.0f / (float)N_NODES;
    float mu = stats[o] * invN;
    float var = stats[16 + o] * invN - mu * mu;
    var = fmaxf(var, 0.0f);
    float g = gamma[o];
    float bt = beta[o];
    float x = out[idx];
    float y = fmaf(g * (x - mu), rsqrtf(var + EPS), bt);
    out[idx] = (y >= 0.0f) ? y : SLOPE * y;
}

extern "C" void kernel_launch(void* const* d_in, const int* in_sizes, int n_in,
                              void* d_out, int out_size, void* d_ws, size_t ws_size,
                              hipStream_t stream)
{
    const float* v = (const float*)d_in[0];
    const float* e = (const float*)d_in[1];
    const int* edge_index = (const int*)d_in[2];
    const float* enet_w = (const float*)d_in[3];
    const float* enet_b = (const float*)d_in[4];
    const float* root = (const float*)d_in[5];
    const float* bias = (const float*)d_in[6];
    const float* gamma = (const float*)d_in[7];
    const float* beta = (const float*)d_in[8];
    float* out = (float*)d_out;

    float* summed = (float*)d_ws;                 // N*16 floats
    float* cnt = summed + (size_t)N_NODES * 16;   // N floats
    float* stats = cnt + N_NODES;                 // 32 floats (sum[16], sumsq[16])

    size_t zero_bytes = ((size_t)N_NODES * 17 + 32) * sizeof(float);
    hipMemsetAsync(d_ws, 0, zero_bytes, stream);

    edge_kernel<<<(N_EDGES + 255) / 256, 256, 0, stream>>>(
        v, e, edge_index, enet_w, enet_b, summed, cnt);

    node_kernel<<<(N_NODES + 255) / 256, 256, 0, stream>>>(
        v, summed, cnt, root, bias, out, stats);

    final_kernel<<<(N_NODES * 16 + 255) / 256, 256, 0, stream>>>(
        out, stats, gamma, beta);
}

// Round 2
// 980.921 us; speedup vs baseline: 1.0090x; 1.0090x over previous
//
#include <hip/hip_runtime.h>

#define N_NODES 100000
#define N_EDGES 1000000
#define EPS 1e-5f
#define SLOPE 0.01f

// ---------------------------------------------------------------------------
// Kernel 1: per-edge message computation + atomic scatter.
// Uses unsafeAtomicAdd -> native global_atomic_add_f32 (no CAS loop).
// W/b indices are wave-uniform -> s_load + SGPR-operand v_fma (VALU cheap).
// ---------------------------------------------------------------------------
__global__ __launch_bounds__(256) void edge_kernel(
    const float* __restrict__ v,
    const float* __restrict__ efeat,
    const int* __restrict__ edge_index,
    const float* __restrict__ enet_w,
    const float* __restrict__ enet_b,
    float* __restrict__ summed,
    int* __restrict__ cnt)
{
    int eid = blockIdx.x * 256 + threadIdx.x;
    if (eid >= N_EDGES) return;

    int src = edge_index[eid];
    int dst = edge_index[N_EDGES + eid];

    float4 ef = *(const float4*)(efeat + (size_t)eid * 4);

    float vsrc[16];
    #pragma unroll
    for (int i = 0; i < 4; ++i) {
        float4 t = *(const float4*)(v + (size_t)src * 16 + i * 4);
        vsrc[i * 4 + 0] = t.x;
        vsrc[i * 4 + 1] = t.y;
        vsrc[i * 4 + 2] = t.z;
        vsrc[i * 4 + 3] = t.w;
    }

    float acc[16];
    #pragma unroll
    for (int o = 0; o < 16; ++o) acc[o] = 0.0f;

    #pragma unroll
    for (int i = 0; i < 16; ++i) {
        float vi = vsrc[i];
        #pragma unroll
        for (int o = 0; o < 16; ++o) {
            const int r = i * 16 + o;
            float w = enet_b[r];
            w = fmaf(ef.x, enet_w[r * 4 + 0], w);
            w = fmaf(ef.y, enet_w[r * 4 + 1], w);
            w = fmaf(ef.z, enet_w[r * 4 + 2], w);
            w = fmaf(ef.w, enet_w[r * 4 + 3], w);
            acc[o] = fmaf(vi, w, acc[o]);
        }
    }

    float* sbase = summed + (size_t)dst * 16;
    #pragma unroll
    for (int o = 0; o < 16; ++o) unsafeAtomicAdd(sbase + o, acc[o]);
    atomicAdd(cnt + dst, 1);
}

// ---------------------------------------------------------------------------
// Kernel 2: per-node: mean + root transform + bias -> d_out (pre-BN),
// plus per-column sum / sumsq reduction into stats[32].
// ---------------------------------------------------------------------------
__global__ __launch_bounds__(256) void node_kernel(
    const float* __restrict__ v,
    const float* __restrict__ summed,
    const int* __restrict__ cnt,
    const float* __restrict__ root,
    const float* __restrict__ bias,
    float* __restrict__ out,
    float* __restrict__ stats)
{
    int n = blockIdx.x * 256 + threadIdx.x;
    bool active = (n < N_NODES);

    float val[16];
    if (active) {
        float vn[16];
        #pragma unroll
        for (int i = 0; i < 4; ++i) {
            float4 t = *(const float4*)(v + (size_t)n * 16 + i * 4);
            vn[i * 4 + 0] = t.x;
            vn[i * 4 + 1] = t.y;
            vn[i * 4 + 2] = t.z;
            vn[i * 4 + 3] = t.w;
        }
        float c = (float)cnt[n];
        float scale = 1.0f / fmaxf(c, 1.0f);
        #pragma unroll
        for (int o = 0; o < 16; ++o) {
            float a = fmaf(summed[(size_t)n * 16 + o], scale, bias[o]);
            #pragma unroll
            for (int i = 0; i < 16; ++i)
                a = fmaf(vn[i], root[i * 16 + o], a);
            val[o] = a;
        }
        #pragma unroll
        for (int i = 0; i < 4; ++i) {
            float4 t = make_float4(val[i * 4 + 0], val[i * 4 + 1],
                                   val[i * 4 + 2], val[i * 4 + 3]);
            *(float4*)(out + (size_t)n * 16 + i * 4) = t;
        }
    } else {
        #pragma unroll
        for (int o = 0; o < 16; ++o) val[o] = 0.0f;
    }

    // wave-level butterfly reduction of sum and sumsq per column
    float ssum[16], ssq[16];
    #pragma unroll
    for (int o = 0; o < 16; ++o) {
        float a = val[o];
        float b = a * a;
        #pragma unroll
        for (int m = 1; m < 64; m <<= 1) {
            a += __shfl_xor(a, m, 64);
            b += __shfl_xor(b, m, 64);
        }
        ssum[o] = a;
        ssq[o] = b;
    }

    __shared__ float part[4][32];
    int wave = threadIdx.x >> 6;
    int lane = threadIdx.x & 63;
    if (lane == 0) {
        #pragma unroll
        for (int o = 0; o < 16; ++o) {
            part[wave][o] = ssum[o];
            part[wave][16 + o] = ssq[o];
        }
    }
    __syncthreads();
    if (threadIdx.x < 32) {
        float t = part[0][threadIdx.x] + part[1][threadIdx.x] +
                  part[2][threadIdx.x] + part[3][threadIdx.x];
        unsafeAtomicAdd(stats + threadIdx.x, t);
    }
}

// ---------------------------------------------------------------------------
// Kernel 3: BatchNorm (batch stats) + LeakyReLU, in place on d_out.
// ---------------------------------------------------------------------------
__global__ __launch_bounds__(256) void final_kernel(
    float* __restrict__ out,
    const float* __restrict__ stats,
    const float* __restrict__ gamma,
    const float* __restrict__ beta)
{
    int idx = blockIdx.x * 256 + threadIdx.x;
    if (idx >= N_NODES * 16) return;
    int o = idx & 15;
    const float invN = 1.0f / (float)N_NODES;
    float mu = stats[o] * invN;
    float var = stats[16 + o] * invN - mu * mu;
    var = fmaxf(var, 0.0f);
    float g = gamma[o];
    float bt = beta[o];
    float x = out[idx];
    float y = fmaf(g * (x - mu), rsqrtf(var + EPS), bt);
    out[idx] = (y >= 0.0f) ? y : SLOPE * y;
}

extern "C" void kernel_launch(void* const* d_in, const int* in_sizes, int n_in,
                              void* d_out, int out_size, void* d_ws, size_t ws_size,
                              hipStream_t stream)
{
    const float* v = (const float*)d_in[0];
    const float* e = (const float*)d_in[1];
    const int* edge_index = (const int*)d_in[2];
    const float* enet_w = (const float*)d_in[3];
    const float* enet_b = (const float*)d_in[4];
    const float* root = (const float*)d_in[5];
    const float* bias = (const float*)d_in[6];
    const float* gamma = (const float*)d_in[7];
    const float* beta = (const float*)d_in[8];
    float* out = (float*)d_out;

    float* summed = (float*)d_ws;                 // N*16 floats
    int* cnt = (int*)(summed + (size_t)N_NODES * 16);   // N ints
    float* stats = (float*)(cnt + N_NODES);       // 32 floats (sum[16], sumsq[16])

    size_t zero_bytes = ((size_t)N_NODES * 17 + 32) * sizeof(float);
    hipMemsetAsync(d_ws, 0, zero_bytes, stream);

    edge_kernel<<<(N_EDGES + 255) / 256, 256, 0, stream>>>(
        v, e, edge_index, enet_w, enet_b, summed, cnt);

    node_kernel<<<(N_NODES + 255) / 256, 256, 0, stream>>>(
        v, summed, cnt, root, bias, out, stats);

    final_kernel<<<(N_NODES * 16 + 255) / 256, 256, 0, stream>>>(
        out, stats, gamma, beta);
}

// Round 3
// 303.841 us; speedup vs baseline: 3.2574x; 3.2284x over previous
//
#include <hip/hip_runtime.h>

#define N_NODES 100000
#define N_EDGES 1000000
#define EPS 1e-5f
#define SLOPE 0.01f
#define NBLK 391  // ceil(N_NODES/256)

// ---------------------------------------------------------------------------
// ws layout (all 4-byte elements, 16B-aligned sections):
//   Y        : N*80 floats (32 MB)   per-node factorized weights
//   rank     : E ints      (4 MB)
//   perm     : E ints      (4 MB)
//   hist     : N ints      (400 KB)  [zeroed] -> in-degree after rank_kernel
//   stats    : 32 floats   [zeroed]  sum[16], sumsq[16]
//   row_part : N ints                block-local exclusive scan of hist
//   bsum     : 512 ints              per-block totals
//   bsum_ex  : 512 ints              exclusive scan of bsum
// ---------------------------------------------------------------------------

// Kernel 1: per-node factorized weights Y[n] = [v·B, v·W0, v·W1, v·W2, v·W3]
__global__ __launch_bounds__(256) void y_kernel(
    const float* __restrict__ v,
    const float* __restrict__ enet_w,
    const float* __restrict__ enet_b,
    float* __restrict__ Y)
{
    int n = blockIdx.x * 256 + threadIdx.x;
    if (n >= N_NODES) return;

    float vn[16];
    #pragma unroll
    for (int i = 0; i < 4; ++i) {
        float4 t = *(const float4*)(v + (size_t)n * 16 + i * 4);
        vn[i * 4 + 0] = t.x; vn[i * 4 + 1] = t.y;
        vn[i * 4 + 2] = t.z; vn[i * 4 + 3] = t.w;
    }

    float* yrow = Y + (size_t)n * 80;

    // bias-term block: y0[o] = sum_i vn[i] * b[i*16+o]   (uniform b -> SGPR)
    #pragma unroll
    for (int o4 = 0; o4 < 4; ++o4) {
        float a0 = 0, a1 = 0, a2 = 0, a3 = 0;
        #pragma unroll
        for (int i = 0; i < 16; ++i) {
            int base = i * 16 + o4 * 4;
            a0 = fmaf(vn[i], enet_b[base + 0], a0);
            a1 = fmaf(vn[i], enet_b[base + 1], a1);
            a2 = fmaf(vn[i], enet_b[base + 2], a2);
            a3 = fmaf(vn[i], enet_b[base + 3], a3);
        }
        *(float4*)(yrow + o4 * 4) = make_float4(a0, a1, a2, a3);
    }
    // yk[o] = sum_i vn[i] * W[(i*16+o)*4 + k]
    #pragma unroll
    for (int k = 0; k < 4; ++k) {
        #pragma unroll
        for (int o4 = 0; o4 < 4; ++o4) {
            float a0 = 0, a1 = 0, a2 = 0, a3 = 0;
            #pragma unroll
            for (int i = 0; i < 16; ++i) {
                int base = (i * 16 + o4 * 4) * 4 + k;
                a0 = fmaf(vn[i], enet_w[base + 0], a0);
                a1 = fmaf(vn[i], enet_w[base + 4], a1);
                a2 = fmaf(vn[i], enet_w[base + 8], a2);
                a3 = fmaf(vn[i], enet_w[base + 12], a3);
            }
            *(float4*)(yrow + 16 + k * 16 + o4 * 4) = make_float4(a0, a1, a2, a3);
        }
    }
}

// Kernel 2: per-edge rank within its dst bucket; hist becomes in-degree.
__global__ __launch_bounds__(256) void rank_kernel(
    const int* __restrict__ edge_index,
    int* __restrict__ hist,
    int* __restrict__ rank)
{
    int eid = blockIdx.x * 256 + threadIdx.x;
    if (eid >= N_EDGES) return;
    int dst = edge_index[N_EDGES + eid];
    rank[eid] = atomicAdd(hist + dst, 1);
}

// Kernel 3: block-local exclusive scan of hist (256/block) + block sums.
__global__ __launch_bounds__(256) void scan1_kernel(
    const int* __restrict__ hist,
    int* __restrict__ row_part,
    int* __restrict__ bsum)
{
    __shared__ int s[256];
    int tid = threadIdx.x;
    int idx = blockIdx.x * 256 + tid;
    int val = (idx < N_NODES) ? hist[idx] : 0;
    s[tid] = val;
    __syncthreads();
    #pragma unroll
    for (int off = 1; off < 256; off <<= 1) {
        int t = (tid >= off) ? s[tid - off] : 0;
        __syncthreads();
        s[tid] += t;
        __syncthreads();
    }
    if (idx < N_NODES) row_part[idx] = s[tid] - val;  // exclusive within block
    if (tid == 255) bsum[blockIdx.x] = s[255];
}

// Kernel 4: exclusive scan of the 391 block sums (single block of 512).
__global__ __launch_bounds__(512) void scan2_kernel(
    const int* __restrict__ bsum,
    int* __restrict__ bsum_ex)
{
    __shared__ int s[512];
    int tid = threadIdx.x;
    int val = (tid < NBLK) ? bsum[tid] : 0;
    s[tid] = val;
    __syncthreads();
    #pragma unroll
    for (int off = 1; off < 512; off <<= 1) {
        int t = (tid >= off) ? s[tid - off] : 0;
        __syncthreads();
        s[tid] += t;
        __syncthreads();
    }
    bsum_ex[tid] = s[tid] - val;
}

// Kernel 5: scatter edge ids into CSR order (plain stores, no atomics).
__global__ __launch_bounds__(256) void perm_kernel(
    const int* __restrict__ edge_index,
    const int* __restrict__ rank,
    const int* __restrict__ row_part,
    const int* __restrict__ bsum_ex,
    int* __restrict__ perm)
{
    int eid = blockIdx.x * 256 + threadIdx.x;
    if (eid >= N_EDGES) return;
    int dst = edge_index[N_EDGES + eid];
    int slot = row_part[dst] + bsum_ex[dst >> 8] + rank[eid];
    perm[slot] = eid;
}

// Kernel 6: per-node pull-gather of messages + mean + root + bias -> out,
// plus per-column sum/sumsq reduction into stats.
__global__ __launch_bounds__(256) void gather_kernel(
    const float* __restrict__ v,
    const float* __restrict__ efeat,
    const int* __restrict__ edge_index,
    const float* __restrict__ Y,
    const int* __restrict__ perm,
    const int* __restrict__ hist,
    const int* __restrict__ row_part,
    const int* __restrict__ bsum_ex,
    const float* __restrict__ root,
    const float* __restrict__ bias,
    float* __restrict__ out,
    float* __restrict__ stats)
{
    int n = blockIdx.x * 256 + threadIdx.x;
    bool active = (n < N_NODES);

    float val[16];
    if (active) {
        int start = row_part[n] + bsum_ex[n >> 8];
        int deg = hist[n];

        float acc[16];
        #pragma unroll
        for (int o = 0; o < 16; ++o) acc[o] = 0.0f;

        for (int j = 0; j < deg; ++j) {
            int eid = perm[start + j];
            float4 ef = *(const float4*)(efeat + (size_t)eid * 4);
            int src = edge_index[eid];
            const float* y = Y + (size_t)src * 80;
            #pragma unroll
            for (int c = 0; c < 4; ++c) {
                float4 y0 = *(const float4*)(y + c * 4);
                float4 y1 = *(const float4*)(y + 16 + c * 4);
                float4 y2 = *(const float4*)(y + 32 + c * 4);
                float4 y3 = *(const float4*)(y + 48 + c * 4);
                float4 y4 = *(const float4*)(y + 64 + c * 4);
                acc[c*4+0] += y0.x + ef.x*y1.x + ef.y*y2.x + ef.z*y3.x + ef.w*y4.x;
                acc[c*4+1] += y0.y + ef.x*y1.y + ef.y*y2.y + ef.z*y3.y + ef.w*y4.y;
                acc[c*4+2] += y0.z + ef.x*y1.z + ef.y*y2.z + ef.z*y3.z + ef.w*y4.z;
                acc[c*4+3] += y0.w + ef.x*y1.w + ef.y*y2.w + ef.z*y3.w + ef.w*y4.w;
            }
        }

        float vn[16];
        #pragma unroll
        for (int i = 0; i < 4; ++i) {
            float4 t = *(const float4*)(v + (size_t)n * 16 + i * 4);
            vn[i * 4 + 0] = t.x; vn[i * 4 + 1] = t.y;
            vn[i * 4 + 2] = t.z; vn[i * 4 + 3] = t.w;
        }
        float scale = 1.0f / fmaxf((float)deg, 1.0f);
        #pragma unroll
        for (int o = 0; o < 16; ++o) {
            float a = fmaf(acc[o], scale, bias[o]);
            #pragma unroll
            for (int i = 0; i < 16; ++i)
                a = fmaf(vn[i], root[i * 16 + o], a);
            val[o] = a;
        }
        #pragma unroll
        for (int i = 0; i < 4; ++i) {
            *(float4*)(out + (size_t)n * 16 + i * 4) =
                make_float4(val[i*4+0], val[i*4+1], val[i*4+2], val[i*4+3]);
        }
    } else {
        #pragma unroll
        for (int o = 0; o < 16; ++o) val[o] = 0.0f;
    }

    // wave butterfly + LDS reduction of sum / sumsq per column
    float ssum[16], ssq[16];
    #pragma unroll
    for (int o = 0; o < 16; ++o) {
        float a = val[o];
        float b = a * a;
        #pragma unroll
        for (int m = 1; m < 64; m <<= 1) {
            a += __shfl_xor(a, m, 64);
            b += __shfl_xor(b, m, 64);
        }
        ssum[o] = a; ssq[o] = b;
    }
    __shared__ float part[4][32];
    int wave = threadIdx.x >> 6;
    int lane = threadIdx.x & 63;
    if (lane == 0) {
        #pragma unroll
        for (int o = 0; o < 16; ++o) {
            part[wave][o] = ssum[o];
            part[wave][16 + o] = ssq[o];
        }
    }
    __syncthreads();
    if (threadIdx.x < 32) {
        float t = part[0][threadIdx.x] + part[1][threadIdx.x] +
                  part[2][threadIdx.x] + part[3][threadIdx.x];
        unsafeAtomicAdd(stats + threadIdx.x, t);
    }
}

// Kernel 7: BatchNorm (batch stats) + LeakyReLU, in place on d_out.
__global__ __launch_bounds__(256) void final_kernel(
    float* __restrict__ out,
    const float* __restrict__ stats,
    const float* __restrict__ gamma,
    const float* __restrict__ beta)
{
    int idx = blockIdx.x * 256 + threadIdx.x;
    if (idx >= N_NODES * 16) return;
    int o = idx & 15;
    const float invN = 1.0f / (float)N_NODES;
    float mu = stats[o] * invN;
    float var = stats[16 + o] * invN - mu * mu;
    var = fmaxf(var, 0.0f);
    float x = out[idx];
    float y = fmaf(gamma[o] * (x - mu), rsqrtf(var + EPS), beta[o]);
    out[idx] = (y >= 0.0f) ? y : SLOPE * y;
}

extern "C" void kernel_launch(void* const* d_in, const int* in_sizes, int n_in,
                              void* d_out, int out_size, void* d_ws, size_t ws_size,
                              hipStream_t stream)
{
    const float* v = (const float*)d_in[0];
    const float* e = (const float*)d_in[1];
    const int* edge_index = (const int*)d_in[2];
    const float* enet_w = (const float*)d_in[3];
    const float* enet_b = (const float*)d_in[4];
    const float* root = (const float*)d_in[5];
    const float* bias = (const float*)d_in[6];
    const float* gamma = (const float*)d_in[7];
    const float* beta = (const float*)d_in[8];
    float* out = (float*)d_out;

    char* ws = (char*)d_ws;
    float* Y       = (float*)ws;                      ws += (size_t)N_NODES * 80 * 4;
    int*   rank    = (int*)ws;                        ws += (size_t)N_EDGES * 4;
    int*   perm    = (int*)ws;                        ws += (size_t)N_EDGES * 4;
    int*   hist    = (int*)ws;                        ws += (size_t)N_NODES * 4;
    float* stats   = (float*)ws;                      ws += 32 * 4;
    int*   row_part= (int*)ws;                        ws += (size_t)N_NODES * 4;
    int*   bsum    = (int*)ws;                        ws += 512 * 4;
    int*   bsum_ex = (int*)ws;

    // zero hist + stats (contiguous)
    hipMemsetAsync(hist, 0, (size_t)N_NODES * 4 + 32 * 4, stream);

    y_kernel<<<NBLK, 256, 0, stream>>>(v, enet_w, enet_b, Y);
    rank_kernel<<<(N_EDGES + 255) / 256, 256, 0, stream>>>(edge_index, hist, rank);
    scan1_kernel<<<NBLK, 256, 0, stream>>>(hist, row_part, bsum);
    scan2_kernel<<<1, 512, 0, stream>>>(bsum, bsum_ex);
    perm_kernel<<<(N_EDGES + 255) / 256, 256, 0, stream>>>(
        edge_index, rank, row_part, bsum_ex, perm);
    gather_kernel<<<NBLK, 256, 0, stream>>>(
        v, e, edge_index, Y, perm, hist, row_part, bsum_ex, root, bias, out, stats);
    final_kernel<<<(N_NODES * 16 + 255) / 256, 256, 0, stream>>>(
        out, stats, gamma, beta);
}

// Round 4
// 243.190 us; speedup vs baseline: 4.0698x; 1.2494x over previous
//
#include <hip/hip_runtime.h>

#define N_NODES 100000
#define N_EDGES 1000000
#define EPS 1e-5f
#define SLOPE 0.01f
#define NBLK 391   // ceil(N_NODES/256)
#define GBLK 1563  // ceil(N_NODES/64) for gather (5 threads/node, 320/block)

// ---------------------------------------------------------------------------
// ws layout:
//   S        : N*80 floats (32 MB)  per-node aggregated outer products
//   rank     : E ints
//   perm     : E ints
//   hist     : N ints     [zeroed] -> in-degree
//   stats    : 32 floats  [zeroed] sum[16], sumsq[16]
//   row_part : N ints
//   bsum     : 512 ints
//   bsum_ex  : 512 ints
// ---------------------------------------------------------------------------

// Kernel 1: per-edge rank within dst bucket; hist becomes in-degree.
__global__ __launch_bounds__(256) void rank_kernel(
    const int* __restrict__ edge_index,
    int* __restrict__ hist,
    int* __restrict__ rank)
{
    int eid = blockIdx.x * 256 + threadIdx.x;
    if (eid >= N_EDGES) return;
    int dst = edge_index[N_EDGES + eid];
    rank[eid] = atomicAdd(hist + dst, 1);
}

// Kernel 2: block-local exclusive scan of hist + block sums.
__global__ __launch_bounds__(256) void scan1_kernel(
    const int* __restrict__ hist,
    int* __restrict__ row_part,
    int* __restrict__ bsum)
{
    __shared__ int s[256];
    int tid = threadIdx.x;
    int idx = blockIdx.x * 256 + tid;
    int val = (idx < N_NODES) ? hist[idx] : 0;
    s[tid] = val;
    __syncthreads();
    #pragma unroll
    for (int off = 1; off < 256; off <<= 1) {
        int t = (tid >= off) ? s[tid - off] : 0;
        __syncthreads();
        s[tid] += t;
        __syncthreads();
    }
    if (idx < N_NODES) row_part[idx] = s[tid] - val;
    if (tid == 255) bsum[blockIdx.x] = s[255];
}

// Kernel 3: exclusive scan of block sums (single block of 512).
__global__ __launch_bounds__(512) void scan2_kernel(
    const int* __restrict__ bsum,
    int* __restrict__ bsum_ex)
{
    __shared__ int s[512];
    int tid = threadIdx.x;
    int val = (tid < NBLK) ? bsum[tid] : 0;
    s[tid] = val;
    __syncthreads();
    #pragma unroll
    for (int off = 1; off < 512; off <<= 1) {
        int t = (tid >= off) ? s[tid - off] : 0;
        __syncthreads();
        s[tid] += t;
        __syncthreads();
    }
    bsum_ex[tid] = s[tid] - val;
}

// Kernel 4: scatter edge ids into CSR order (plain stores).
__global__ __launch_bounds__(256) void perm_kernel(
    const int* __restrict__ edge_index,
    const int* __restrict__ rank,
    const int* __restrict__ row_part,
    const int* __restrict__ bsum_ex,
    int* __restrict__ perm)
{
    int eid = blockIdx.x * 256 + threadIdx.x;
    if (eid >= N_EDGES) return;
    int dst = edge_index[N_EDGES + eid];
    int slot = row_part[dst] + bsum_ex[dst >> 8] + rank[eid];
    perm[slot] = eid;
}

// ---------------------------------------------------------------------------
// Kernel 5: S[n] = sum over incoming edges of outer(v[src], [1, ef]).
// 5 threads per node: thread t accumulates component t (16 floats).
// All random reads hit small arrays (v = 6.4 MB -> L2/L3 resident).
// ---------------------------------------------------------------------------
__global__ __launch_bounds__(320) void gather_s_kernel(
    const float* __restrict__ v,
    const float* __restrict__ efeat,
    const int* __restrict__ edge_index,
    const int* __restrict__ perm,
    const int* __restrict__ hist,
    const int* __restrict__ row_part,
    const int* __restrict__ bsum_ex,
    float* __restrict__ S)
{
    int tid = blockIdx.x * 320 + threadIdx.x;
    int n = tid / 5;
    int t = tid % 5;
    if (n >= N_NODES) return;

    int start = row_part[n] + bsum_ex[n >> 8];
    int deg = hist[n];

    float acc[16];
    #pragma unroll
    for (int i = 0; i < 16; ++i) acc[i] = 0.0f;

    for (int j = 0; j < deg; ++j) {
        int eid = perm[start + j];
        int src = edge_index[eid];
        float4 ef = *(const float4*)(efeat + (size_t)eid * 4);
        float c = 1.0f;
        c = (t == 1) ? ef.x : c;
        c = (t == 2) ? ef.y : c;
        c = (t == 3) ? ef.z : c;
        c = (t == 4) ? ef.w : c;
        const float* vp = v + (size_t)src * 16;
        #pragma unroll
        for (int i = 0; i < 4; ++i) {
            float4 tv = *(const float4*)(vp + i * 4);
            acc[i*4+0] = fmaf(c, tv.x, acc[i*4+0]);
            acc[i*4+1] = fmaf(c, tv.y, acc[i*4+1]);
            acc[i*4+2] = fmaf(c, tv.z, acc[i*4+2]);
            acc[i*4+3] = fmaf(c, tv.w, acc[i*4+3]);
        }
    }

    float* sp = S + (size_t)n * 80 + t * 16;
    #pragma unroll
    for (int i = 0; i < 4; ++i)
        *(float4*)(sp + i * 4) = make_float4(acc[i*4+0], acc[i*4+1],
                                             acc[i*4+2], acc[i*4+3]);
}

// ---------------------------------------------------------------------------
// Kernel 6: per-node: summed = S0*B + sum_k Sk*Wk; mean + root + bias -> out;
// per-column sum/sumsq reduction into stats. Weights are wave-uniform -> SGPR.
// ---------------------------------------------------------------------------
__global__ __launch_bounds__(256) void node_kernel(
    const float* __restrict__ v,
    const float* __restrict__ S,
    const int* __restrict__ hist,
    const float* __restrict__ enet_w,
    const float* __restrict__ enet_b,
    const float* __restrict__ root,
    const float* __restrict__ bias,
    float* __restrict__ out,
    float* __restrict__ stats)
{
    int n = blockIdx.x * 256 + threadIdx.x;
    bool active = (n < N_NODES);

    float val[16];
    if (active) {
        float s[80];
        #pragma unroll
        for (int i = 0; i < 20; ++i) {
            float4 tv = *(const float4*)(S + (size_t)n * 80 + i * 4);
            s[i*4+0] = tv.x; s[i*4+1] = tv.y; s[i*4+2] = tv.z; s[i*4+3] = tv.w;
        }
        float vn[16];
        #pragma unroll
        for (int i = 0; i < 4; ++i) {
            float4 tv = *(const float4*)(v + (size_t)n * 16 + i * 4);
            vn[i*4+0] = tv.x; vn[i*4+1] = tv.y; vn[i*4+2] = tv.z; vn[i*4+3] = tv.w;
        }
        float scale = 1.0f / fmaxf((float)hist[n], 1.0f);

        #pragma unroll
        for (int o = 0; o < 16; ++o) {
            float a = 0.0f;
            #pragma unroll
            for (int i = 0; i < 16; ++i) {
                a = fmaf(s[i], enet_b[i * 16 + o], a);           // S0 * B
                #pragma unroll
                for (int k = 0; k < 4; ++k)
                    a = fmaf(s[16 + k * 16 + i],
                             enet_w[(i * 16 + o) * 4 + k], a);   // Sk * Wk
            }
            a = fmaf(a, scale, bias[o]);
            #pragma unroll
            for (int i = 0; i < 16; ++i)
                a = fmaf(vn[i], root[i * 16 + o], a);
            val[o] = a;
        }
        #pragma unroll
        for (int i = 0; i < 4; ++i)
            *(float4*)(out + (size_t)n * 16 + i * 4) =
                make_float4(val[i*4+0], val[i*4+1], val[i*4+2], val[i*4+3]);
    } else {
        #pragma unroll
        for (int o = 0; o < 16; ++o) val[o] = 0.0f;
    }

    // wave butterfly + LDS reduction of sum / sumsq per column
    float ssum[16], ssq[16];
    #pragma unroll
    for (int o = 0; o < 16; ++o) {
        float a = val[o];
        float b = a * a;
        #pragma unroll
        for (int m = 1; m < 64; m <<= 1) {
            a += __shfl_xor(a, m, 64);
            b += __shfl_xor(b, m, 64);
        }
        ssum[o] = a; ssq[o] = b;
    }
    __shared__ float part[4][32];
    int wave = threadIdx.x >> 6;
    int lane = threadIdx.x & 63;
    if (lane == 0) {
        #pragma unroll
        for (int o = 0; o < 16; ++o) {
            part[wave][o] = ssum[o];
            part[wave][16 + o] = ssq[o];
        }
    }
    __syncthreads();
    if (threadIdx.x < 32) {
        float t = part[0][threadIdx.x] + part[1][threadIdx.x] +
                  part[2][threadIdx.x] + part[3][threadIdx.x];
        unsafeAtomicAdd(stats + threadIdx.x, t);
    }
}

// Kernel 7: BatchNorm (batch stats) + LeakyReLU, in place on d_out.
__global__ __launch_bounds__(256) void final_kernel(
    float* __restrict__ out,
    const float* __restrict__ stats,
    const float* __restrict__ gamma,
    const float* __restrict__ beta)
{
    int idx = blockIdx.x * 256 + threadIdx.x;
    if (idx >= N_NODES * 16) return;
    int o = idx & 15;
    const float invN = 1.0f / (float)N_NODES;
    float mu = stats[o] * invN;
    float var = stats[16 + o] * invN - mu * mu;
    var = fmaxf(var, 0.0f);
    float x = out[idx];
    float y = fmaf(gamma[o] * (x - mu), rsqrtf(var + EPS), beta[o]);
    out[idx] = (y >= 0.0f) ? y : SLOPE * y;
}

extern "C" void kernel_launch(void* const* d_in, const int* in_sizes, int n_in,
                              void* d_out, int out_size, void* d_ws, size_t ws_size,
                              hipStream_t stream)
{
    const float* v = (const float*)d_in[0];
    const float* e = (const float*)d_in[1];
    const int* edge_index = (const int*)d_in[2];
    const float* enet_w = (const float*)d_in[3];
    const float* enet_b = (const float*)d_in[4];
    const float* root = (const float*)d_in[5];
    const float* bias = (const float*)d_in[6];
    const float* gamma = (const float*)d_in[7];
    const float* beta = (const float*)d_in[8];
    float* out = (float*)d_out;

    char* ws = (char*)d_ws;
    float* S       = (float*)ws;                      ws += (size_t)N_NODES * 80 * 4;
    int*   rank    = (int*)ws;                        ws += (size_t)N_EDGES * 4;
    int*   perm    = (int*)ws;                        ws += (size_t)N_EDGES * 4;
    int*   hist    = (int*)ws;                        ws += (size_t)N_NODES * 4;
    float* stats   = (float*)ws;                      ws += 32 * 4;
    int*   row_part= (int*)ws;                        ws += (size_t)N_NODES * 4;
    int*   bsum    = (int*)ws;                        ws += 512 * 4;
    int*   bsum_ex = (int*)ws;

    // zero hist + stats (contiguous)
    hipMemsetAsync(hist, 0, (size_t)N_NODES * 4 + 32 * 4, stream);

    rank_kernel<<<(N_EDGES + 255) / 256, 256, 0, stream>>>(edge_index, hist, rank);
    scan1_kernel<<<NBLK, 256, 0, stream>>>(hist, row_part, bsum);
    scan2_kernel<<<1, 512, 0, stream>>>(bsum, bsum_ex);
    perm_kernel<<<(N_EDGES + 255) / 256, 256, 0, stream>>>(
        edge_index, rank, row_part, bsum_ex, perm);
    gather_s_kernel<<<GBLK, 320, 0, stream>>>(
        v, e, edge_index, perm, hist, row_part, bsum_ex, S);
    node_kernel<<<NBLK, 256, 0, stream>>>(
        v, S, hist, enet_w, enet_b, root, bias, out, stats);
    final_kernel<<<(N_NODES * 16 + 255) / 256, 256, 0, stream>>>(
        out, stats, gamma, beta);
}